// Round 3
// baseline (4378.362 us; speedup 1.0000x reference)
//
#include <hip/hip_runtime.h>

// ---------------- problem constants ----------------
constexpr int B_ = 8, N_ = 8192, NPOINT_ = 2048, NSAMPLE_ = 32;
constexpr int M_ROWS = B_ * NPOINT_ * NSAMPLE_;   // 524288
constexpr int NGROUP = B_ * NPOINT_;              // 16384
// ws layout (bytes) — TOTAL 6.3 MB. Defensive vs small ws_size.
constexpr size_t OFF_NXF   = 0;                   // 49152 f32 (f32 mirror of new_xyz)
constexpr size_t OFF_IDX   = 196608;              // 524288 u16 -> ends 1245184
constexpr size_t OFF_WF    = 1245184;             // 16576 f32  -> ends 1311488
constexpr size_t OFF_GB    = 1311488;             // 512 f32    -> ends 1313536
constexpr size_t OFF_STATS = 1313536;             // 512 f32    -> ends 1315584
constexpr size_t OFF_NP    = 1315584;             // 512 f32    -> ends 1317632
constexpr size_t OFF_FLAG  = 1317632;             // 1 i32
constexpr size_t OFF_MAXB  = 2097152;             // 16384*128 bf16 -> ends 6291456

__device__ __forceinline__ float bf2f(unsigned short u) {
  union { unsigned u; float f; } x; x.u = ((unsigned)u) << 16; return x.f;
}
// bf2f of low/high half of a packed u32 — 1 VALU op each, bitwise == bf2f
__device__ __forceinline__ float lo16f(unsigned u) {
  union { unsigned u; float f; } x; x.u = u << 16; return x.f;
}
__device__ __forceinline__ float hi16f(unsigned u) {
  union { unsigned u; float f; } x; x.u = u & 0xffff0000u; return x.f;
}
__device__ __forceinline__ unsigned short f2bf(float f) {
  union { float f; unsigned u; } x; x.f = f;
  unsigned u = x.u + 0x7FFFu + ((x.u >> 16) & 1u);
  return (unsigned short)(u >> 16);
}
__device__ __forceinline__ void unpack8(uint4 u, float* x) {
  x[0] = bf2f((unsigned short)(u.x & 0xffffu)); x[1] = bf2f((unsigned short)(u.x >> 16));
  x[2] = bf2f((unsigned short)(u.y & 0xffffu)); x[3] = bf2f((unsigned short)(u.y >> 16));
  x[4] = bf2f((unsigned short)(u.z & 0xffffu)); x[5] = bf2f((unsigned short)(u.z >> 16));
  x[6] = bf2f((unsigned short)(u.w & 0xffffu)); x[7] = bf2f((unsigned short)(u.w >> 16));
}
// dual-dtype scalar load: element i of tensor p
__device__ __forceinline__ float ldf(const void* p, size_t i, bool bf) {
  return bf ? bf2f(((const unsigned short*)p)[i]) : ((const float*)p)[i];
}
__device__ __forceinline__ void stf(void* p, size_t i, bool bf, float v) {
  if (bf) ((unsigned short*)p)[i] = f2bf(v);
  else    ((float*)p)[i] = v;
}

// ---------------- dtype detector ----------------
extern "C" __global__ void detect_kernel(const unsigned short* __restrict__ xyz,
                                         int* __restrict__ flag) {
  if (threadIdx.x == 0 && blockIdx.x == 0) {
    int sane = 0;
    for (int k = 0; k < 32; ++k) {
      int e = (xyz[2 * k] >> 7) & 0xff;
      if (e >= 90 && e <= 140) ++sane;
    }
    *flag = (sane >= 24) ? 1 : 0;
  }
}

// ---------------- weight / param up-convert ----------------
extern "C" __global__ void prep_kernel(
    const void* W1, const void* W2, const void* W3,
    const void* g1, const void* b1, const void* g2, const void* b2,
    const void* g3, const void* b3,
    float* __restrict__ wf, float* __restrict__ gb, const int* __restrict__ flag) {
  const bool bf = (*flag != 0);
  int i = blockIdx.x * 256 + threadIdx.x;
  if (i < 4288)       wf[i] = ldf(W1, i, bf);
  else if (i < 8384)  wf[i] = ldf(W2, i - 4288, bf);
  else if (i < 16576) wf[i] = ldf(W3, i - 8384, bf);
  else if (i < 17088) {
    int k = i - 16576; float v;
    if (k < 64)       v = ldf(g1, k, bf);
    else if (k < 128) v = ldf(b1, k - 64, bf);
    else if (k < 192) v = ldf(g2, k - 128, bf);
    else if (k < 256) v = ldf(b2, k - 192, bf);
    else if (k < 384) v = ldf(g3, k - 256, bf);
    else              v = ldf(b3, k - 384, bf);
    gb[k] = v;
  }
}

// ---------------- furthest point sampling (v5) ----------------
// R2 counters: VGPR_Count=56 even with launch_bounds(512,2) -> the compiler
// REMATERIALIZES the 64 live point floats from memory every iteration (pre-RA
// sinking ignores the waves-per-eu cap). v5 fixes:
//  * bf path keeps coords PACKED: 24 u32 regs (2 bf16 each, loaded as 6 uint4).
//    Unpack = 1 VALU op/coord (<<16 or &0xffff0000) — bitwise == bf2f.
//  * asm volatile "+v" pins on cc[24]+d[16] each iteration: marks values as
//    modified so the memory copy is stale -> remat across iterations illegal.
//  * hot loop is v_min+v_max only; winning-k rescan runs in a divergent branch
//    that 7/8 waves execz-skip. Tie-break (lowest index) preserved exactly:
//    descending-k equality scan + lowest-lane ballot.
template <bool BF>
__device__ __forceinline__ void fps_body(
    const void* xyz, void* out, float* __restrict__ nxf,
    unsigned short* sxyz, float (*sv)[8], int (*si)[8]) {
#pragma clang fp contract(off)
  const int b = blockIdx.x;
  const int t = threadIdx.x;
  const int lane = t & 63, w = t >> 6;
  const size_t base = (size_t)b * N_ * 3;
  unsigned cc[24];                             // packed bf16 coords (BF path)
  float px[16], py[16], pz[16];                // f32 path only
  float d[16];
  if (BF) {
    const uint4* xp = (const uint4*)((const unsigned short*)xyz + base) + t * 6;
    uint4* sp = (uint4*)sxyz + t * 6;
#pragma unroll
    for (int m = 0; m < 6; ++m) {
      uint4 u = xp[m];
      sp[m] = u;                               // LDS mirror (broadcast reads)
      cc[4*m+0] = u.x; cc[4*m+1] = u.y; cc[4*m+2] = u.z; cc[4*m+3] = u.w;
    }
  } else {
#pragma unroll
    for (int k = 0; k < 16; ++k) {
      int i = t * 16 + k;
      px[k] = ((const float*)xyz)[base + i*3 + 0];
      py[k] = ((const float*)xyz)[base + i*3 + 1];
      pz[k] = ((const float*)xyz)[base + i*3 + 2];
    }
  }
#pragma unroll
  for (int k = 0; k < 16; ++k) d[k] = 1e10f;
  __syncthreads();                             // mirror ready
  // register ring buffer for selected centers: thread (j&511) owns j, slot j>>9
  float s0x=0.f,s0y=0.f,s0z=0.f, s1x=0.f,s1y=0.f,s1z=0.f,
        s2x=0.f,s2y=0.f,s2z=0.f, s3x=0.f,s3y=0.f,s3z=0.f;
  // j = 0 picks point 0 — broadcast read (LDS for bf, global for f32)
  float p0, p1, p2;
  if (BF) { p0 = bf2f(sxyz[0]); p1 = bf2f(sxyz[1]); p2 = bf2f(sxyz[2]); }
  else {
    p0 = ((const float*)xyz)[base + 0];
    p1 = ((const float*)xyz)[base + 1];
    p2 = ((const float*)xyz)[base + 2];
  }
  if (t == 0) { s0x = p0; s0y = p1; s0z = p2; }
  for (int j = 1; j < NPOINT_; ++j) {
    // ---- residency pins: kill cross-iteration remat/spill of array state
    if (BF) {
#pragma unroll
      for (int m = 0; m < 24; ++m) asm volatile("" : "+v"(cc[m]));
    } else {
#pragma unroll
      for (int k = 0; k < 16; ++k)
        asm volatile("" : "+v"(px[k]), "+v"(py[k]), "+v"(pz[k]));
    }
#pragma unroll
    for (int m = 0; m < 16; ++m) asm volatile("" : "+v"(d[m]));
    float bv = -1.0f;
#pragma unroll
    for (int k = 0; k < 16; ++k) {
      float x, y, z;
      if (BF) {
        if ((k & 1) == 0) {
          unsigned ra = cc[(3*k) >> 1], rb = cc[((3*k) >> 1) + 1];
          x = lo16f(ra); y = hi16f(ra); z = lo16f(rb);
        } else {
          unsigned ra = cc[(3*k - 1) >> 1], rb = cc[(3*k + 1) >> 1];
          x = hi16f(ra); y = lo16f(rb); z = hi16f(rb);
        }
      } else { x = px[k]; y = py[k]; z = pz[k]; }
      float dx = x - p0, dy = y - p1, dz = z - p2;
      float d2 = (dx*dx + dy*dy) + dz*dz;     // plain ops: match numpy bitwise
      float dn = fminf(d[k], d2);
      d[k] = dn;
      bv = fmaxf(bv, dn);                     // value-only max in hot loop
    }
    float bv0 = bv;
#pragma unroll
    for (int off = 1; off < 64; off <<= 1)    // value-only butterfly max
      bv = fmaxf(bv, __shfl_xor(bv, off));
    int bk = 0;
    if (bv0 == bv) {                          // 7/8 waves execz-skip this
#pragma unroll
      for (int k = 15; k >= 0; --k)           // desc scan -> lowest matching k
        if (d[k] == bv0) bk = k;
    }
    unsigned long long m = __ballot(bv0 == bv);
    int sl = (int)__builtin_ctzll(m);         // lowest lane == lowest index
    int pi = __shfl(t * 16 + bk, sl);
    const int pb = j & 1;
    if (lane == 0) { sv[pb][w] = bv; si[pb][w] = pi; }
    __syncthreads();                           // the ONLY barrier per iteration
    // all threads scan the 8 wave winners (strict > keeps lowest wave/index)
    float gv = sv[pb][0]; int gpi = si[pb][0];
#pragma unroll
    for (int q = 1; q < 8; ++q) {
      float v2 = sv[pb][q]; int i2 = si[pb][q];
      if (v2 > gv) { gv = v2; gpi = i2; }
    }
    // winner coords: same-address broadcast (LDS bf path / global f32 path)
    if (BF) {
      int wo3 = gpi * 3;
      p0 = bf2f(sxyz[wo3 + 0]); p1 = bf2f(sxyz[wo3 + 1]); p2 = bf2f(sxyz[wo3 + 2]);
    } else {
      size_t wo = base + (size_t)gpi * 3;
      p0 = ((const float*)xyz)[wo + 0];
      p1 = ((const float*)xyz)[wo + 1];
      p2 = ((const float*)xyz)[wo + 2];
    }
    if (t == (j & 511)) {                     // bank center j (static slots)
      const int s = j >> 9;
      if      (s == 0) { s0x = p0; s0y = p1; s0z = p2; }
      else if (s == 1) { s1x = p0; s1y = p1; s1z = p2; }
      else if (s == 2) { s2x = p0; s2y = p1; s2z = p2; }
      else             { s3x = p0; s3y = p1; s3z = p2; }
    }
  }
  // flush all 2048 selected centers (4 per thread, fully parallel)
  const bool bfrt = BF;
#pragma unroll
  for (int s = 0; s < 4; ++s) {
    float cx = (s==0)?s0x:(s==1)?s1x:(s==2)?s2x:s3x;
    float cy = (s==0)?s0y:(s==1)?s1y:(s==2)?s2y:s3y;
    float cz = (s==0)?s0z:(s==1)?s1z:(s==2)?s2z:s3z;
    size_t o = ((size_t)b * NPOINT_ + s * 512 + t) * 3;
    nxf[o+0] = cx; nxf[o+1] = cy; nxf[o+2] = cz;
    stf(out, o+0, bfrt, cx); stf(out, o+1, bfrt, cy); stf(out, o+2, bfrt, cz);
  }
}

extern "C" __global__ void __launch_bounds__(512, 2) fps_kernel(
    const void* xyz, void* out, float* __restrict__ nxf,
    const int* __restrict__ flag) {
  __shared__ unsigned short sxyz[N_ * 3];     // 48KB bf16 mirror (bf path only)
  __shared__ float sv[2][8];
  __shared__ int   si[2][8];
  if (*flag != 0) fps_body<true>(xyz, out, nxf, sxyz, sv, si);
  else            fps_body<false>(xyz, out, nxf, sxyz, sv, si);
}

// ---------------- ball query: one wave per center ----------------
extern "C" __global__ void __launch_bounds__(256) ballq_kernel(
    const void* xyz, const float* __restrict__ nxf,
    unsigned short* __restrict__ idxout, const int* __restrict__ flag) {
#pragma clang fp contract(off)
  const bool bf = (*flag != 0);
  const int gw = (int)((blockIdx.x * 256 + threadIdx.x) >> 6);
  const int lane = threadIdx.x & 63;
  const int b = gw >> 11;
  const int j = gw & (NPOINT_ - 1);
  const size_t base = (size_t)b * N_ * 3;
  const size_t co = ((size_t)b * NPOINT_ + j) * 3;
  const float c0 = nxf[co], c1 = nxf[co+1], c2 = nxf[co+2];
  unsigned short* out = idxout + (size_t)gw * NSAMPLE_;
  int cnt = 0, first = 0;
  for (int c = 0; c < N_/64 && cnt < NSAMPLE_; ++c) {
    int i = c * 64 + lane;
    float x = ldf(xyz, base + i*3 + 0, bf);
    float y = ldf(xyz, base + i*3 + 1, bf);
    float z = ldf(xyz, base + i*3 + 2, bf);
    float dx = x - c0, dy = y - c1, dz = z - c2;
    float d2 = (dx*dx + dy*dy) + dz*dz;
    unsigned long long m = __ballot(d2 < 0.16f);
    if (lane == 0) {
      while (m && cnt < NSAMPLE_) {
        int bit = __builtin_ctzll(m);
        int pi = c * 64 + bit;
        if (cnt == 0) first = pi;
        out[cnt] = (unsigned short)pi;
        ++cnt;
        m &= (m - 1);
      }
    }
    cnt = __shfl(cnt, 0);
  }
  first = __shfl(first, 0);
  if (lane >= cnt && lane < NSAMPLE_) out[lane] = (unsigned short)first;
}

// ---------------- shared row-compute building blocks ----------------
// Streams the 64-ch points row in 8-elem chunks (keeps x-liveness at 8 regs).
__device__ __forceinline__ void l1_row(
    const void* xyz, const void* points, const float* __restrict__ nxf,
    const unsigned short* __restrict__ idx, const float* __restrict__ wf,
    int r, bool bf, float* acc) {
  const int b = r >> 16;                       // 65536 rows per batch
  const int j = (r >> 5) & (NPOINT_ - 1);
  const int i = idx[r];
  const size_t pt = (size_t)b * N_ + i;
  const float* cp = nxf + ((size_t)b * NPOINT_ + j) * 3;
  float f0 = ldf(xyz, pt*3 + 0, bf) - cp[0];
  float f1 = ldf(xyz, pt*3 + 1, bf) - cp[1];
  float f2 = ldf(xyz, pt*3 + 2, bf) - cp[2];
#pragma unroll
  for (int c = 0; c < 64; ++c)
    acc[c] = fmaf(f0, wf[c], fmaf(f1, wf[64+c], f2 * wf[128+c]));
  const float* wp = wf + 192;
  if (bf) {
    const uint4* pp = (const uint4*)((const unsigned short*)points + pt * 64);
#pragma unroll
    for (int s = 0; s < 8; ++s) {
      uint4 u = pp[s];
      float x[8]; unpack8(u, x);
#pragma unroll
      for (int kk = 0; kk < 8; ++kk)
#pragma unroll
        for (int c = 0; c < 64; ++c)
          acc[c] = fmaf(x[kk], wp[(s*8+kk)*64 + c], acc[c]);
    }
  } else {
    const float4* pp = (const float4*)((const float*)points + pt * 64);
#pragma unroll
    for (int s = 0; s < 16; ++s) {
      float4 u = pp[s];
      float x[4] = {u.x, u.y, u.z, u.w};
#pragma unroll
      for (int kk = 0; kk < 4; ++kk)
#pragma unroll
        for (int c = 0; c < 64; ++c)
          acc[c] = fmaf(x[kk], wp[(s*4+kk)*64 + c], acc[c]);
    }
  }
}

template <int LDW>
__device__ __forceinline__ void mm64(const float* v, const float* __restrict__ w,
                                     float* acc) {
#pragma unroll
  for (int ch = 0; ch < 64; ++ch)
#pragma unroll
    for (int c = 0; c < 64; ++c)
      acc[c] = fmaf(v[ch], w[ch*LDW + c], acc[c]);
}

__device__ __forceinline__ void bnrelu64(float* v, const float* __restrict__ np0) {
#pragma unroll
  for (int c = 0; c < 64; ++c)
    v[c] = fmaxf(fmaf(v[c], np0[c], np0[64 + c]), 0.f);
}

// wave butterfly-sum of 64-elem array + its squares, LDS combine, block atomics
__device__ __forceinline__ void commit_stats64(float* a, float* __restrict__ stats) {
  float q[64];
#pragma unroll
  for (int c = 0; c < 64; ++c) q[c] = a[c] * a[c];
#pragma unroll
  for (int off = 1; off < 64; off <<= 1)
#pragma unroll
    for (int c = 0; c < 64; ++c) {
      a[c] += __shfl_xor(a[c], off);
      q[c] += __shfl_xor(q[c], off);
    }
  __shared__ float LS[4][64], LQ[4][64];
  const int t = threadIdx.x, w = t >> 6;
  if ((t & 63) == 0) {
#pragma unroll
    for (int c = 0; c < 64; ++c) { LS[w][c] = a[c]; LQ[w][c] = q[c]; }
  }
  __syncthreads();
  if (t < 64) {
    atomicAdd(&stats[t],      LS[0][t] + LS[1][t] + LS[2][t] + LS[3][t]);
    atomicAdd(&stats[64 + t], LQ[0][t] + LQ[1][t] + LQ[2][t] + LQ[3][t]);
  }
}

// ---------------- pass 1: L1 row -> stats only ----------------
extern "C" __global__ void __launch_bounds__(256) p1_kernel(
    const void* xyz, const void* points, const float* __restrict__ nxf,
    const unsigned short* __restrict__ idx, const float* __restrict__ wf,
    float* __restrict__ stats, const int* __restrict__ flag) {
  const bool bf = (*flag != 0);
  const int r = blockIdx.x * 256 + threadIdx.x;
  float acc[64];
  l1_row(xyz, points, nxf, idx, wf, r, bf, acc);
  commit_stats64(acc, stats);
}

// ---------------- pass 2: L1 -> BN1 -> L2 -> stats ----------------
// (256,2): cap 256 VGPRs — v[64]+acc[64]+temps ≈ 140 live floats must not spill
extern "C" __global__ void __launch_bounds__(256, 2) p2_kernel(
    const void* xyz, const void* points, const float* __restrict__ nxf,
    const unsigned short* __restrict__ idx, const float* __restrict__ wf,
    const float* __restrict__ w2, const float* __restrict__ np1,
    float* __restrict__ stats, const int* __restrict__ flag) {
  const bool bf = (*flag != 0);
  const int r = blockIdx.x * 256 + threadIdx.x;
  float v[64];
  l1_row(xyz, points, nxf, idx, wf, r, bf, v);
  bnrelu64(v, np1);
  float acc[64];
#pragma unroll
  for (int c = 0; c < 64; ++c) acc[c] = 0.f;
  mm64<64>(v, w2, acc);
  commit_stats64(acc, stats);
}

// ---------------- pass 3: L1->BN1->L2->BN2->L3 + group max + stats ----------
// (256,2): cap 256 VGPRs — v+y2+y3 = 192 live floats must not spill
extern "C" __global__ void __launch_bounds__(256, 2) p3_kernel(
    const void* xyz, const void* points, const float* __restrict__ nxf,
    const unsigned short* __restrict__ idx, const float* __restrict__ wf,
    const float* __restrict__ w2, const float* __restrict__ w3,
    const float* __restrict__ np1, const float* __restrict__ np2,
    unsigned short* __restrict__ maxb, float* __restrict__ stats,
    const int* __restrict__ flag) {
  const bool bf = (*flag != 0);
  const int t = threadIdx.x, lane = t & 63, w = t >> 6;
  const int h = __builtin_amdgcn_readfirstlane(w & 1);
  const int g = blockIdx.x * 4 + (w >> 1) * 2 + (lane >> 5);
  const int r = g * 32 + (lane & 31);
  float v[64];
  l1_row(xyz, points, nxf, idx, wf, r, bf, v);
  bnrelu64(v, np1);
  float y2[64];
#pragma unroll
  for (int c = 0; c < 64; ++c) y2[c] = 0.f;
  mm64<64>(v, w2, y2);
  bnrelu64(y2, np2);
  const float* w3h = w3 + h * 64;
  float y3[64];
#pragma unroll
  for (int c = 0; c < 64; ++c) y3[c] = 0.f;
  mm64<128>(y2, w3h, y3);
  float* s = v; float* q = y2;                 // reuse registers
#pragma unroll
  for (int c = 0; c < 64; ++c) { s[c] = y3[c]; q[c] = y3[c] * y3[c]; }
  // group max over 32-lane halves on raw y3
#pragma unroll
  for (int off = 1; off <= 16; off <<= 1)
#pragma unroll
    for (int c = 0; c < 64; ++c)
      y3[c] = fmaxf(y3[c], __shfl_xor(y3[c], off));
  if ((lane & 31) == 0) {
    unsigned short* mo = maxb + (size_t)g * 128 + h * 64;
#pragma unroll
    for (int c = 0; c < 64; ++c) mo[c] = f2bf(y3[c]);
  }
  // stats: sum over full wave (both 32-row groups share channel-half h)
#pragma unroll
  for (int off = 1; off < 64; off <<= 1)
#pragma unroll
    for (int c = 0; c < 64; ++c) {
      s[c] += __shfl_xor(s[c], off);
      q[c] += __shfl_xor(q[c], off);
    }
  __shared__ float LS[4][64], LQ[4][64];
  if (lane == 0) {
#pragma unroll
    for (int c = 0; c < 64; ++c) { LS[w][c] = s[c]; LQ[w][c] = q[c]; }
  }
  __syncthreads();
  if (t < 128) {
    int hh = t >> 6, cl = t & 63;
    atomicAdd(&stats[t],       LS[hh][cl] + LS[hh+2][cl]);
    atomicAdd(&stats[128 + t], LQ[hh][cl] + LQ[hh+2][cl]);
  }
}

// ---------------- fold stats into (scale, shift) ----------------
extern "C" __global__ void nparam_kernel(
    const float* __restrict__ stats, const float* __restrict__ g,
    const float* __restrict__ bb, float* __restrict__ npar, int Cc) {
  int c = threadIdx.x;
  if (c < Cc) {
    float m = stats[c] * (1.0f / M_ROWS);
    float v = stats[Cc + c] * (1.0f / M_ROWS) - m * m;
    float sc = g[c] / sqrtf(v + 1e-5f);
    npar[c] = sc;
    npar[Cc + c] = bb[c] - m * sc;
  }
}

// ---------------- final: affine+relu on raw maxima -> out ----------------
extern "C" __global__ void __launch_bounds__(256) final_kernel(
    const unsigned short* __restrict__ maxb, const float* __restrict__ npar,
    void* out, const int* __restrict__ flag) {
  const bool bf = (*flag != 0);
  const int gtid = blockIdx.x * 256 + threadIdx.x;
  const int c = gtid & 127;
  float y = bf2f(maxb[gtid]);
  float r = fmaxf(fmaf(y, npar[c], npar[128 + c]), 0.f);
  stf(out, (size_t)B_ * NPOINT_ * 3 + gtid, bf, r);
}

extern "C" void kernel_launch(void* const* d_in, const int* in_sizes, int n_in,
                              void* d_out, int out_size, void* d_ws, size_t ws_size,
                              hipStream_t stream) {
  const void* xyz    = d_in[0];
  const void* points = d_in[1];
  char* ws = (char*)d_ws;
  float* nxf   = (float*)(ws + OFF_NXF);
  unsigned short* wsIdx = (unsigned short*)(ws + OFF_IDX);
  float* wf    = (float*)(ws + OFF_WF);
  float* gb    = (float*)(ws + OFF_GB);
  float* stats = (float*)(ws + OFF_STATS);
  float* npar  = (float*)(ws + OFF_NP);
  int*   flag  = (int*)(ws + OFF_FLAG);
  unsigned short* maxb = (unsigned short*)(ws + OFF_MAXB);

  hipMemsetAsync(stats, 0, 512 * sizeof(float), stream);
  detect_kernel<<<1, 64, 0, stream>>>((const unsigned short*)xyz, flag);
  prep_kernel<<<67, 256, 0, stream>>>(d_in[2], d_in[5], d_in[8], d_in[3], d_in[4],
                                      d_in[6], d_in[7], d_in[9], d_in[10], wf, gb, flag);
  fps_kernel<<<B_, 512, 0, stream>>>(xyz, d_out, nxf, flag);
  ballq_kernel<<<(B_ * NPOINT_) / 4, 256, 0, stream>>>(xyz, nxf, wsIdx, flag);
  p1_kernel<<<M_ROWS / 256, 256, 0, stream>>>(xyz, points, nxf, wsIdx, wf, stats, flag);
  nparam_kernel<<<1, 128, 0, stream>>>(stats, gb, gb + 64, npar, 64);
  p2_kernel<<<M_ROWS / 256, 256, 0, stream>>>(xyz, points, nxf, wsIdx, wf, wf + 4288,
                                              npar, stats + 128, flag);
  nparam_kernel<<<1, 128, 0, stream>>>(stats + 128, gb + 128, gb + 192, npar + 128, 64);
  p3_kernel<<<(2 * M_ROWS) / 256, 256, 0, stream>>>(xyz, points, nxf, wsIdx, wf,
                                                    wf + 4288, wf + 8384, npar,
                                                    npar + 128, maxb, stats + 256, flag);
  nparam_kernel<<<1, 128, 0, stream>>>(stats + 256, gb + 256, gb + 384, npar + 256, 128);
  final_kernel<<<(NGROUP * 128) / 256, 256, 0, stream>>>(maxb, npar + 256, d_out, flag);
}

// Round 4
// 4234.813 us; speedup vs baseline: 1.0339x; 1.0339x over previous
//
#include <hip/hip_runtime.h>

// ---------------- problem constants ----------------
constexpr int B_ = 8, N_ = 8192, NPOINT_ = 2048, NSAMPLE_ = 32;
constexpr int M_ROWS = B_ * NPOINT_ * NSAMPLE_;   // 524288
constexpr int NGROUP = B_ * NPOINT_;              // 16384
// ws layout (bytes) — TOTAL 6.3 MB. Defensive vs small ws_size.
constexpr size_t OFF_NXF   = 0;                   // 49152 f32 (f32 mirror of new_xyz)
constexpr size_t OFF_IDX   = 196608;              // 524288 u16 -> ends 1245184
constexpr size_t OFF_WF    = 1245184;             // 16576 f32  -> ends 1311488
constexpr size_t OFF_GB    = 1311488;             // 512 f32    -> ends 1313536
constexpr size_t OFF_STATS = 1313536;             // 512 f32    -> ends 1315584
constexpr size_t OFF_NP    = 1315584;             // 512 f32    -> ends 1317632
constexpr size_t OFF_FLAG  = 1317632;             // 1 i32
constexpr size_t OFF_MAXB  = 2097152;             // 16384*128 bf16 -> ends 6291456

__device__ __forceinline__ float bf2f(unsigned short u) {
  union { unsigned u; float f; } x; x.u = ((unsigned)u) << 16; return x.f;
}
// bf2f of low/high half of a packed u32 — 1 VALU op each, bitwise == bf2f
__device__ __forceinline__ float lo16f(unsigned u) {
  union { unsigned u; float f; } x; x.u = u << 16; return x.f;
}
__device__ __forceinline__ float hi16f(unsigned u) {
  union { unsigned u; float f; } x; x.u = u & 0xffff0000u; return x.f;
}
__device__ __forceinline__ unsigned short f2bf(float f) {
  union { float f; unsigned u; } x; x.f = f;
  unsigned u = x.u + 0x7FFFu + ((x.u >> 16) & 1u);
  return (unsigned short)(u >> 16);
}
__device__ __forceinline__ void unpack8(uint4 u, float* x) {
  x[0] = bf2f((unsigned short)(u.x & 0xffffu)); x[1] = bf2f((unsigned short)(u.x >> 16));
  x[2] = bf2f((unsigned short)(u.y & 0xffffu)); x[3] = bf2f((unsigned short)(u.y >> 16));
  x[4] = bf2f((unsigned short)(u.z & 0xffffu)); x[5] = bf2f((unsigned short)(u.z >> 16));
  x[6] = bf2f((unsigned short)(u.w & 0xffffu)); x[7] = bf2f((unsigned short)(u.w >> 16));
}
// dual-dtype scalar load: element i of tensor p
__device__ __forceinline__ float ldf(const void* p, size_t i, bool bf) {
  return bf ? bf2f(((const unsigned short*)p)[i]) : ((const float*)p)[i];
}
__device__ __forceinline__ void stf(void* p, size_t i, bool bf, float v) {
  if (bf) ((unsigned short*)p)[i] = f2bf(v);
  else    ((float*)p)[i] = v;
}

// ---------------- dtype detector ----------------
extern "C" __global__ void detect_kernel(const unsigned short* __restrict__ xyz,
                                         int* __restrict__ flag) {
  if (threadIdx.x == 0 && blockIdx.x == 0) {
    int sane = 0;
    for (int k = 0; k < 32; ++k) {
      int e = (xyz[2 * k] >> 7) & 0xff;
      if (e >= 90 && e <= 140) ++sane;
    }
    *flag = (sane >= 24) ? 1 : 0;
  }
}

// ---------------- weight / param up-convert ----------------
extern "C" __global__ void prep_kernel(
    const void* W1, const void* W2, const void* W3,
    const void* g1, const void* b1, const void* g2, const void* b2,
    const void* g3, const void* b3,
    float* __restrict__ wf, float* __restrict__ gb, const int* __restrict__ flag) {
  const bool bf = (*flag != 0);
  int i = blockIdx.x * 256 + threadIdx.x;
  if (i < 4288)       wf[i] = ldf(W1, i, bf);
  else if (i < 8384)  wf[i] = ldf(W2, i - 4288, bf);
  else if (i < 16576) wf[i] = ldf(W3, i - 8384, bf);
  else if (i < 17088) {
    int k = i - 16576; float v;
    if (k < 64)       v = ldf(g1, k, bf);
    else if (k < 128) v = ldf(b1, k - 64, bf);
    else if (k < 192) v = ldf(g2, k - 128, bf);
    else if (k < 256) v = ldf(b2, k - 192, bf);
    else if (k < 384) v = ldf(g3, k - 256, bf);
    else              v = ldf(b3, k - 384, bf);
    gb[k] = v;
  }
}

// ---------------- furthest point sampling (v6) ----------------
// R3 post-mortem: VGPR fits (64) yet time unchanged -> NOT spill-bound; it's
// latency-bound with only 2 waves/SIMD to hide the serial reduce chain
// (6 dependent ds_swizzle + barrier + LDS scan + winner fetch ~ 1500+ cyc).
// v6: 1024 threads (16 waves = 4/SIMD) — same total VALU work per CU, but
// half the per-wave serial work and 2x the TLP to hide the chain. State is
// cc[12]+d[8] (bf, packed) / px,py,pz,d[8] (f32) — resident at the 128-reg
// (1024,4) cap without pins (pins regressed R3: they are scheduling fences).
// Tie-break semantics preserved exactly: contiguous point ownership, strict >
// in-loop argmax (lowest k), lowest-lane ballot, ordered 16-entry scan.
template <bool BF>
__device__ __forceinline__ void fps_body(
    const void* xyz, void* out, float* __restrict__ nxf,
    unsigned short* sxyz, float (*sv)[16], int (*si)[16]) {
#pragma clang fp contract(off)
  const int b = blockIdx.x;
  const int t = threadIdx.x;
  const int lane = t & 63, w = t >> 6;
  const size_t base = (size_t)b * N_ * 3;
  unsigned cc[12];                             // packed bf16 coords (BF path)
  float px[8], py[8], pz[8];                   // f32 path only
  float d[8];
  if (BF) {
    const uint4* xp = (const uint4*)((const unsigned short*)xyz + base) + t * 3;
    uint4* sp = (uint4*)sxyz + t * 3;
#pragma unroll
    for (int m = 0; m < 3; ++m) {
      uint4 u = xp[m];
      sp[m] = u;                               // LDS mirror (broadcast reads)
      cc[4*m+0] = u.x; cc[4*m+1] = u.y; cc[4*m+2] = u.z; cc[4*m+3] = u.w;
    }
  } else {
#pragma unroll
    for (int k = 0; k < 8; ++k) {
      int i = t * 8 + k;
      px[k] = ((const float*)xyz)[base + i*3 + 0];
      py[k] = ((const float*)xyz)[base + i*3 + 1];
      pz[k] = ((const float*)xyz)[base + i*3 + 2];
    }
  }
#pragma unroll
  for (int k = 0; k < 8; ++k) d[k] = 1e10f;
  __syncthreads();                             // mirror ready
  // register ring for selected centers: thread (j&1023) owns j, slot j>>10
  float s0x=0.f,s0y=0.f,s0z=0.f, s1x=0.f,s1y=0.f,s1z=0.f;
  // j = 0 picks point 0 — broadcast read (LDS for bf, global for f32)
  float p0, p1, p2;
  if (BF) { p0 = bf2f(sxyz[0]); p1 = bf2f(sxyz[1]); p2 = bf2f(sxyz[2]); }
  else {
    p0 = ((const float*)xyz)[base + 0];
    p1 = ((const float*)xyz)[base + 1];
    p2 = ((const float*)xyz)[base + 2];
  }
  if (t == 0) { s0x = p0; s0y = p1; s0z = p2; }
  for (int j = 1; j < NPOINT_; ++j) {
    float bv = -1.0f; int bk = 0;
#pragma unroll
    for (int k = 0; k < 8; ++k) {
      float x, y, z;
      if (BF) {
        if ((k & 1) == 0) {
          unsigned ra = cc[(3*k) >> 1], rb = cc[((3*k) >> 1) + 1];
          x = lo16f(ra); y = hi16f(ra); z = lo16f(rb);
        } else {
          unsigned ra = cc[(3*k - 1) >> 1], rb = cc[(3*k + 1) >> 1];
          x = hi16f(ra); y = lo16f(rb); z = hi16f(rb);
        }
      } else { x = px[k]; y = py[k]; z = pz[k]; }
      float dx = x - p0, dy = y - p1, dz = z - p2;
      float d2 = (dx*dx + dy*dy) + dz*dz;     // plain ops: match numpy bitwise
      float dn = fminf(d[k], d2);
      d[k] = dn;
      if (dn > bv) { bv = dn; bk = k; }       // strict >: first occurrence
    }
    float bv0 = bv;
#pragma unroll
    for (int off = 1; off < 64; off <<= 1)    // value-only butterfly max
      bv = fmaxf(bv, __shfl_xor(bv, off));
    unsigned long long m = __ballot(bv0 == bv);
    int sl = (int)__builtin_ctzll(m);         // lowest lane == lowest index
    int pi = __shfl(t * 8 + bk, sl);
    const int pb = j & 1;
    if (lane == 0) { sv[pb][w] = bv; si[pb][w] = pi; }
    __syncthreads();                           // the ONLY barrier per iteration
    // all threads scan the 16 wave winners (strict > keeps lowest wave/index)
    float gv = sv[pb][0]; int gpi = si[pb][0];
#pragma unroll
    for (int q = 1; q < 16; ++q) {
      float v2 = sv[pb][q]; int i2 = si[pb][q];
      if (v2 > gv) { gv = v2; gpi = i2; }
    }
    // winner coords: same-address broadcast (LDS bf path / global f32 path)
    if (BF) {
      int wo3 = gpi * 3;
      p0 = bf2f(sxyz[wo3 + 0]); p1 = bf2f(sxyz[wo3 + 1]); p2 = bf2f(sxyz[wo3 + 2]);
    } else {
      size_t wo = base + (size_t)gpi * 3;
      p0 = ((const float*)xyz)[wo + 0];
      p1 = ((const float*)xyz)[wo + 1];
      p2 = ((const float*)xyz)[wo + 2];
    }
    if (t == (j & 1023)) {                    // bank center j (static slots)
      if ((j >> 10) == 0) { s0x = p0; s0y = p1; s0z = p2; }
      else                { s1x = p0; s1y = p1; s1z = p2; }
    }
  }
  // flush all 2048 selected centers (2 per thread, fully parallel)
  const bool bfrt = BF;
#pragma unroll
  for (int s = 0; s < 2; ++s) {
    float cx = (s==0)?s0x:s1x;
    float cy = (s==0)?s0y:s1y;
    float cz = (s==0)?s0z:s1z;
    size_t o = ((size_t)b * NPOINT_ + s * 1024 + t) * 3;
    nxf[o+0] = cx; nxf[o+1] = cy; nxf[o+2] = cz;
    stf(out, o+0, bfrt, cx); stf(out, o+1, bfrt, cy); stf(out, o+2, bfrt, cz);
  }
}

extern "C" __global__ void __launch_bounds__(1024, 4) fps_kernel(
    const void* xyz, void* out, float* __restrict__ nxf,
    const int* __restrict__ flag) {
  __shared__ unsigned short sxyz[N_ * 3];     // 48KB bf16 mirror (bf path only)
  __shared__ float sv[2][16];
  __shared__ int   si[2][16];
  if (*flag != 0) fps_body<true>(xyz, out, nxf, sxyz, sv, si);
  else            fps_body<false>(xyz, out, nxf, sxyz, sv, si);
}

// ---------------- ball query: one wave per center ----------------
extern "C" __global__ void __launch_bounds__(256) ballq_kernel(
    const void* xyz, const float* __restrict__ nxf,
    unsigned short* __restrict__ idxout, const int* __restrict__ flag) {
#pragma clang fp contract(off)
  const bool bf = (*flag != 0);
  const int gw = (int)((blockIdx.x * 256 + threadIdx.x) >> 6);
  const int lane = threadIdx.x & 63;
  const int b = gw >> 11;
  const int j = gw & (NPOINT_ - 1);
  const size_t base = (size_t)b * N_ * 3;
  const size_t co = ((size_t)b * NPOINT_ + j) * 3;
  const float c0 = nxf[co], c1 = nxf[co+1], c2 = nxf[co+2];
  unsigned short* out = idxout + (size_t)gw * NSAMPLE_;
  int cnt = 0, first = 0;
  for (int c = 0; c < N_/64 && cnt < NSAMPLE_; ++c) {
    int i = c * 64 + lane;
    float x = ldf(xyz, base + i*3 + 0, bf);
    float y = ldf(xyz, base + i*3 + 1, bf);
    float z = ldf(xyz, base + i*3 + 2, bf);
    float dx = x - c0, dy = y - c1, dz = z - c2;
    float d2 = (dx*dx + dy*dy) + dz*dz;
    unsigned long long m = __ballot(d2 < 0.16f);
    if (lane == 0) {
      while (m && cnt < NSAMPLE_) {
        int bit = __builtin_ctzll(m);
        int pi = c * 64 + bit;
        if (cnt == 0) first = pi;
        out[cnt] = (unsigned short)pi;
        ++cnt;
        m &= (m - 1);
      }
    }
    cnt = __shfl(cnt, 0);
  }
  first = __shfl(first, 0);
  if (lane >= cnt && lane < NSAMPLE_) out[lane] = (unsigned short)first;
}

// ---------------- shared row-compute building blocks ----------------
// Streams the 64-ch points row in 8-elem chunks (keeps x-liveness at 8 regs).
__device__ __forceinline__ void l1_row(
    const void* xyz, const void* points, const float* __restrict__ nxf,
    const unsigned short* __restrict__ idx, const float* __restrict__ wf,
    int r, bool bf, float* acc) {
  const int b = r >> 16;                       // 65536 rows per batch
  const int j = (r >> 5) & (NPOINT_ - 1);
  const int i = idx[r];
  const size_t pt = (size_t)b * N_ + i;
  const float* cp = nxf + ((size_t)b * NPOINT_ + j) * 3;
  float f0 = ldf(xyz, pt*3 + 0, bf) - cp[0];
  float f1 = ldf(xyz, pt*3 + 1, bf) - cp[1];
  float f2 = ldf(xyz, pt*3 + 2, bf) - cp[2];
#pragma unroll
  for (int c = 0; c < 64; ++c)
    acc[c] = fmaf(f0, wf[c], fmaf(f1, wf[64+c], f2 * wf[128+c]));
  const float* wp = wf + 192;
  if (bf) {
    const uint4* pp = (const uint4*)((const unsigned short*)points + pt * 64);
#pragma unroll
    for (int s = 0; s < 8; ++s) {
      uint4 u = pp[s];
      float x[8]; unpack8(u, x);
#pragma unroll
      for (int kk = 0; kk < 8; ++kk)
#pragma unroll
        for (int c = 0; c < 64; ++c)
          acc[c] = fmaf(x[kk], wp[(s*8+kk)*64 + c], acc[c]);
    }
  } else {
    const float4* pp = (const float4*)((const float*)points + pt * 64);
#pragma unroll
    for (int s = 0; s < 16; ++s) {
      float4 u = pp[s];
      float x[4] = {u.x, u.y, u.z, u.w};
#pragma unroll
      for (int kk = 0; kk < 4; ++kk)
#pragma unroll
        for (int c = 0; c < 64; ++c)
          acc[c] = fmaf(x[kk], wp[(s*4+kk)*64 + c], acc[c]);
    }
  }
}

template <int LDW>
__device__ __forceinline__ void mm64(const float* v, const float* __restrict__ w,
                                     float* acc) {
#pragma unroll
  for (int ch = 0; ch < 64; ++ch)
#pragma unroll
    for (int c = 0; c < 64; ++c)
      acc[c] = fmaf(v[ch], w[ch*LDW + c], acc[c]);
}

__device__ __forceinline__ void bnrelu64(float* v, const float* __restrict__ np0) {
#pragma unroll
  for (int c = 0; c < 64; ++c)
    v[c] = fmaxf(fmaf(v[c], np0[c], np0[64 + c]), 0.f);
}

// wave butterfly-sum of 64-elem array + its squares, LDS combine, block atomics
__device__ __forceinline__ void commit_stats64(float* a, float* __restrict__ stats) {
  float q[64];
#pragma unroll
  for (int c = 0; c < 64; ++c) q[c] = a[c] * a[c];
#pragma unroll
  for (int off = 1; off < 64; off <<= 1)
#pragma unroll
    for (int c = 0; c < 64; ++c) {
      a[c] += __shfl_xor(a[c], off);
      q[c] += __shfl_xor(q[c], off);
    }
  __shared__ float LS[4][64], LQ[4][64];
  const int t = threadIdx.x, w = t >> 6;
  if ((t & 63) == 0) {
#pragma unroll
    for (int c = 0; c < 64; ++c) { LS[w][c] = a[c]; LQ[w][c] = q[c]; }
  }
  __syncthreads();
  if (t < 64) {
    atomicAdd(&stats[t],      LS[0][t] + LS[1][t] + LS[2][t] + LS[3][t]);
    atomicAdd(&stats[64 + t], LQ[0][t] + LQ[1][t] + LQ[2][t] + LQ[3][t]);
  }
}

// ---------------- pass 1: L1 row -> stats only ----------------
extern "C" __global__ void __launch_bounds__(256) p1_kernel(
    const void* xyz, const void* points, const float* __restrict__ nxf,
    const unsigned short* __restrict__ idx, const float* __restrict__ wf,
    float* __restrict__ stats, const int* __restrict__ flag) {
  const bool bf = (*flag != 0);
  const int r = blockIdx.x * 256 + threadIdx.x;
  float acc[64];
  l1_row(xyz, points, nxf, idx, wf, r, bf, acc);
  commit_stats64(acc, stats);
}

// ---------------- pass 2: L1 -> BN1 -> L2 -> stats ----------------
// (256,2): cap 256 VGPRs — v[64]+acc[64]+temps ≈ 140 live floats must not spill
extern "C" __global__ void __launch_bounds__(256, 2) p2_kernel(
    const void* xyz, const void* points, const float* __restrict__ nxf,
    const unsigned short* __restrict__ idx, const float* __restrict__ wf,
    const float* __restrict__ w2, const float* __restrict__ np1,
    float* __restrict__ stats, const int* __restrict__ flag) {
  const bool bf = (*flag != 0);
  const int r = blockIdx.x * 256 + threadIdx.x;
  float v[64];
  l1_row(xyz, points, nxf, idx, wf, r, bf, v);
  bnrelu64(v, np1);
  float acc[64];
#pragma unroll
  for (int c = 0; c < 64; ++c) acc[c] = 0.f;
  mm64<64>(v, w2, acc);
  commit_stats64(acc, stats);
}

// ---------------- pass 3: L1->BN1->L2->BN2->L3 + group max + stats ----------
// (256,2): cap 256 VGPRs — v+y2+y3 = 192 live floats must not spill
extern "C" __global__ void __launch_bounds__(256, 2) p3_kernel(
    const void* xyz, const void* points, const float* __restrict__ nxf,
    const unsigned short* __restrict__ idx, const float* __restrict__ wf,
    const float* __restrict__ w2, const float* __restrict__ w3,
    const float* __restrict__ np1, const float* __restrict__ np2,
    unsigned short* __restrict__ maxb, float* __restrict__ stats,
    const int* __restrict__ flag) {
  const bool bf = (*flag != 0);
  const int t = threadIdx.x, lane = t & 63, w = t >> 6;
  const int h = __builtin_amdgcn_readfirstlane(w & 1);
  const int g = blockIdx.x * 4 + (w >> 1) * 2 + (lane >> 5);
  const int r = g * 32 + (lane & 31);
  float v[64];
  l1_row(xyz, points, nxf, idx, wf, r, bf, v);
  bnrelu64(v, np1);
  float y2[64];
#pragma unroll
  for (int c = 0; c < 64; ++c) y2[c] = 0.f;
  mm64<64>(v, w2, y2);
  bnrelu64(y2, np2);
  const float* w3h = w3 + h * 64;
  float y3[64];
#pragma unroll
  for (int c = 0; c < 64; ++c) y3[c] = 0.f;
  mm64<128>(y2, w3h, y3);
  float* s = v; float* q = y2;                 // reuse registers
#pragma unroll
  for (int c = 0; c < 64; ++c) { s[c] = y3[c]; q[c] = y3[c] * y3[c]; }
  // group max over 32-lane halves on raw y3
#pragma unroll
  for (int off = 1; off <= 16; off <<= 1)
#pragma unroll
    for (int c = 0; c < 64; ++c)
      y3[c] = fmaxf(y3[c], __shfl_xor(y3[c], off));
  if ((lane & 31) == 0) {
    unsigned short* mo = maxb + (size_t)g * 128 + h * 64;
#pragma unroll
    for (int c = 0; c < 64; ++c) mo[c] = f2bf(y3[c]);
  }
  // stats: sum over full wave (both 32-row groups share channel-half h)
#pragma unroll
  for (int off = 1; off < 64; off <<= 1)
#pragma unroll
    for (int c = 0; c < 64; ++c) {
      s[c] += __shfl_xor(s[c], off);
      q[c] += __shfl_xor(q[c], off);
    }
  __shared__ float LS[4][64], LQ[4][64];
  if (lane == 0) {
#pragma unroll
    for (int c = 0; c < 64; ++c) { LS[w][c] = s[c]; LQ[w][c] = q[c]; }
  }
  __syncthreads();
  if (t < 128) {
    int hh = t >> 6, cl = t & 63;
    atomicAdd(&stats[t],       LS[hh][cl] + LS[hh+2][cl]);
    atomicAdd(&stats[128 + t], LQ[hh][cl] + LQ[hh+2][cl]);
  }
}

// ---------------- fold stats into (scale, shift) ----------------
extern "C" __global__ void nparam_kernel(
    const float* __restrict__ stats, const float* __restrict__ g,
    const float* __restrict__ bb, float* __restrict__ npar, int Cc) {
  int c = threadIdx.x;
  if (c < Cc) {
    float m = stats[c] * (1.0f / M_ROWS);
    float v = stats[Cc + c] * (1.0f / M_ROWS) - m * m;
    float sc = g[c] / sqrtf(v + 1e-5f);
    npar[c] = sc;
    npar[Cc + c] = bb[c] - m * sc;
  }
}

// ---------------- final: affine+relu on raw maxima -> out ----------------
extern "C" __global__ void __launch_bounds__(256) final_kernel(
    const unsigned short* __restrict__ maxb, const float* __restrict__ npar,
    void* out, const int* __restrict__ flag) {
  const bool bf = (*flag != 0);
  const int gtid = blockIdx.x * 256 + threadIdx.x;
  const int c = gtid & 127;
  float y = bf2f(maxb[gtid]);
  float r = fmaxf(fmaf(y, npar[c], npar[128 + c]), 0.f);
  stf(out, (size_t)B_ * NPOINT_ * 3 + gtid, bf, r);
}

extern "C" void kernel_launch(void* const* d_in, const int* in_sizes, int n_in,
                              void* d_out, int out_size, void* d_ws, size_t ws_size,
                              hipStream_t stream) {
  const void* xyz    = d_in[0];
  const void* points = d_in[1];
  char* ws = (char*)d_ws;
  float* nxf   = (float*)(ws + OFF_NXF);
  unsigned short* wsIdx = (unsigned short*)(ws + OFF_IDX);
  float* wf    = (float*)(ws + OFF_WF);
  float* gb    = (float*)(ws + OFF_GB);
  float* stats = (float*)(ws + OFF_STATS);
  float* npar  = (float*)(ws + OFF_NP);
  int*   flag  = (int*)(ws + OFF_FLAG);
  unsigned short* maxb = (unsigned short*)(ws + OFF_MAXB);

  hipMemsetAsync(stats, 0, 512 * sizeof(float), stream);
  detect_kernel<<<1, 64, 0, stream>>>((const unsigned short*)xyz, flag);
  prep_kernel<<<67, 256, 0, stream>>>(d_in[2], d_in[5], d_in[8], d_in[3], d_in[4],
                                      d_in[6], d_in[7], d_in[9], d_in[10], wf, gb, flag);
  fps_kernel<<<B_, 1024, 0, stream>>>(xyz, d_out, nxf, flag);
  ballq_kernel<<<(B_ * NPOINT_) / 4, 256, 0, stream>>>(xyz, nxf, wsIdx, flag);
  p1_kernel<<<M_ROWS / 256, 256, 0, stream>>>(xyz, points, nxf, wsIdx, wf, stats, flag);
  nparam_kernel<<<1, 128, 0, stream>>>(stats, gb, gb + 64, npar, 64);
  p2_kernel<<<M_ROWS / 256, 256, 0, stream>>>(xyz, points, nxf, wsIdx, wf, wf + 4288,
                                              npar, stats + 128, flag);
  nparam_kernel<<<1, 128, 0, stream>>>(stats + 128, gb + 128, gb + 192, npar + 128, 64);
  p3_kernel<<<(2 * M_ROWS) / 256, 256, 0, stream>>>(xyz, points, nxf, wsIdx, wf,
                                                    wf + 4288, wf + 8384, npar,
                                                    npar + 128, maxb, stats + 256, flag);
  nparam_kernel<<<1, 128, 0, stream>>>(stats + 256, gb + 256, gb + 384, npar + 256, 128);
  final_kernel<<<(NGROUP * 128) / 256, 256, 0, stream>>>(maxb, npar + 256, d_out, flag);
}

// Round 5
// 3822.108 us; speedup vs baseline: 1.1455x; 1.1080x over previous
//
#include <hip/hip_runtime.h>

// ---------------- problem constants ----------------
constexpr int B_ = 8, N_ = 8192, NPOINT_ = 2048, NSAMPLE_ = 32;
constexpr int M_ROWS = B_ * NPOINT_ * NSAMPLE_;   // 524288
constexpr int NGROUP = B_ * NPOINT_;              // 16384
// ws layout (bytes) — TOTAL 6.3 MB. Defensive vs small ws_size.
constexpr size_t OFF_NXF   = 0;                   // 49152 f32 (f32 mirror of new_xyz)
constexpr size_t OFF_IDX   = 196608;              // 524288 u16 -> ends 1245184
constexpr size_t OFF_WF    = 1245184;             // 16576 f32  -> ends 1311488
constexpr size_t OFF_GB    = 1311488;             // 512 f32    -> ends 1313536
constexpr size_t OFF_STATS = 1313536;             // 512 f32    -> ends 1315584
constexpr size_t OFF_NP    = 1315584;             // 512 f32    -> ends 1317632
constexpr size_t OFF_FLAG  = 1317632;             // 1 i32
constexpr size_t OFF_MAXB  = 2097152;             // 16384*128 bf16 -> ends 6291456

__device__ __forceinline__ float bf2f(unsigned short u) {
  union { unsigned u; float f; } x; x.u = ((unsigned)u) << 16; return x.f;
}
// bf2f of low/high half of a packed u32 — 1 VALU op each, bitwise == bf2f
__device__ __forceinline__ float lo16f(unsigned u) {
  union { unsigned u; float f; } x; x.u = u << 16; return x.f;
}
__device__ __forceinline__ float hi16f(unsigned u) {
  union { unsigned u; float f; } x; x.u = u & 0xffff0000u; return x.f;
}
__device__ __forceinline__ unsigned short f2bf(float f) {
  union { float f; unsigned u; } x; x.f = f;
  unsigned u = x.u + 0x7FFFu + ((x.u >> 16) & 1u);
  return (unsigned short)(u >> 16);
}
__device__ __forceinline__ unsigned f2u(float f) {
  union { float f; unsigned u; } x; x.f = f; return x.u;
}
__device__ __forceinline__ void unpack8(uint4 u, float* x) {
  x[0] = bf2f((unsigned short)(u.x & 0xffffu)); x[1] = bf2f((unsigned short)(u.x >> 16));
  x[2] = bf2f((unsigned short)(u.y & 0xffffu)); x[3] = bf2f((unsigned short)(u.y >> 16));
  x[4] = bf2f((unsigned short)(u.z & 0xffffu)); x[5] = bf2f((unsigned short)(u.z >> 16));
  x[6] = bf2f((unsigned short)(u.w & 0xffffu)); x[7] = bf2f((unsigned short)(u.w >> 16));
}
// dual-dtype scalar load: element i of tensor p
__device__ __forceinline__ float ldf(const void* p, size_t i, bool bf) {
  return bf ? bf2f(((const unsigned short*)p)[i]) : ((const float*)p)[i];
}
__device__ __forceinline__ void stf(void* p, size_t i, bool bf, float v) {
  if (bf) ((unsigned short*)p)[i] = f2bf(v);
  else    ((float*)p)[i] = v;
}

// ---------------- dtype detector ----------------
extern "C" __global__ void detect_kernel(const unsigned short* __restrict__ xyz,
                                         int* __restrict__ flag) {
  if (threadIdx.x == 0 && blockIdx.x == 0) {
    int sane = 0;
    for (int k = 0; k < 32; ++k) {
      int e = (xyz[2 * k] >> 7) & 0xff;
      if (e >= 90 && e <= 140) ++sane;
    }
    *flag = (sane >= 24) ? 1 : 0;
  }
}

// ---------------- weight / param up-convert ----------------
extern "C" __global__ void prep_kernel(
    const void* W1, const void* W2, const void* W3,
    const void* g1, const void* b1, const void* g2, const void* b2,
    const void* g3, const void* b3,
    float* __restrict__ wf, float* __restrict__ gb, const int* __restrict__ flag) {
  const bool bf = (*flag != 0);
  int i = blockIdx.x * 256 + threadIdx.x;
  if (i < 4288)       wf[i] = ldf(W1, i, bf);
  else if (i < 8384)  wf[i] = ldf(W2, i - 4288, bf);
  else if (i < 16576) wf[i] = ldf(W3, i - 8384, bf);
  else if (i < 17088) {
    int k = i - 16576; float v;
    if (k < 64)       v = ldf(g1, k, bf);
    else if (k < 128) v = ldf(b1, k - 64, bf);
    else if (k < 192) v = ldf(g2, k - 128, bf);
    else if (k < 256) v = ldf(b2, k - 192, bf);
    else if (k < 384) v = ldf(g3, k - 256, bf);
    else              v = ldf(b3, k - 384, bf);
    gb[k] = v;
  }
}

// ---------------- furthest point sampling (v7) ----------------
// R4 counters: active-CU issue occupancy ~72% -> ISSUE-bound. Dominant issue
// cost was the 2nd-level reduce: every thread read 32 LDS words (sv[16]+
// si[16]) + 45-op serial scan per iteration (~128KB LDS traffic/iter).
// v7: keyed LDS atomic reduce. Per wave, lane0 packs
//   key = (float_bits(wave_max) << 32) | ~pi
// (d2 >= 0 so float bits are order-isomorphic; ~pi makes u64-max tie-break
// to the LOWEST point index == numpy first-occurrence argmax, index-exact).
// 16 ds_max_u64 to one slot, barrier, one broadcast b64 read per thread.
// Slots rotate mod 3: slot (j+1)%3 zeroed in iter j; its last readers were
// iter j-2, separated by barrier(j-1) -> race-free.
// Also: coords unpacked once at init (px/py/pz[8] f32, ~32 state regs at the
// 128-reg (1024,4) cap); inner loop is value-only v_min+v_max; winning k
// recovered by descending-k rescan only on wave-max lanes (execz-skipped).
template <bool BF>
__device__ __forceinline__ void fps_body(
    const void* xyz, void* out, float* __restrict__ nxf,
    unsigned short* sxyz, unsigned long long* slots) {
#pragma clang fp contract(off)
  const int b = blockIdx.x;
  const int t = threadIdx.x;
  const int lane = t & 63;
  const size_t base = (size_t)b * N_ * 3;
  float px[8], py[8], pz[8], d[8];
  if (BF) {
    const uint4* xp = (const uint4*)((const unsigned short*)xyz + base) + t * 3;
    uint4* sp = (uint4*)sxyz + t * 3;
    unsigned cc[12];
#pragma unroll
    for (int m = 0; m < 3; ++m) {
      uint4 u = xp[m];
      sp[m] = u;                               // LDS mirror (broadcast reads)
      cc[4*m+0] = u.x; cc[4*m+1] = u.y; cc[4*m+2] = u.z; cc[4*m+3] = u.w;
    }
#pragma unroll
    for (int k = 0; k < 8; ++k) {              // unpack ONCE (not per-iter)
      if ((k & 1) == 0) {
        unsigned ra = cc[(3*k) >> 1], rb = cc[((3*k) >> 1) + 1];
        px[k] = lo16f(ra); py[k] = hi16f(ra); pz[k] = lo16f(rb);
      } else {
        unsigned ra = cc[(3*k - 1) >> 1], rb = cc[(3*k + 1) >> 1];
        px[k] = hi16f(ra); py[k] = lo16f(rb); pz[k] = hi16f(rb);
      }
    }
  } else {
#pragma unroll
    for (int k = 0; k < 8; ++k) {
      int i = t * 8 + k;
      px[k] = ((const float*)xyz)[base + i*3 + 0];
      py[k] = ((const float*)xyz)[base + i*3 + 1];
      pz[k] = ((const float*)xyz)[base + i*3 + 2];
    }
  }
#pragma unroll
  for (int k = 0; k < 8; ++k) d[k] = 1e10f;
  if (t < 3) slots[t] = 0ull;                  // init all 3 rotation slots
  __syncthreads();                             // mirror + slots ready
  // register ring for selected centers: thread (j&1023) owns j, slot j>>10
  float s0x=0.f,s0y=0.f,s0z=0.f, s1x=0.f,s1y=0.f,s1z=0.f;
  // j = 0 picks point 0 — broadcast read (LDS for bf, global for f32)
  float p0, p1, p2;
  if (BF) { p0 = bf2f(sxyz[0]); p1 = bf2f(sxyz[1]); p2 = bf2f(sxyz[2]); }
  else {
    p0 = ((const float*)xyz)[base + 0];
    p1 = ((const float*)xyz)[base + 1];
    p2 = ((const float*)xyz)[base + 2];
  }
  if (t == 0) { s0x = p0; s0y = p1; s0z = p2; }
  for (int j = 1; j < NPOINT_; ++j) {
    float bv = -1.0f;
#pragma unroll
    for (int k = 0; k < 8; ++k) {              // value-only: v_min + v_max
      float dx = px[k] - p0, dy = py[k] - p1, dz = pz[k] - p2;
      float d2 = (dx*dx + dy*dy) + dz*dz;     // plain ops: match numpy bitwise
      float dn = fminf(d[k], d2);
      d[k] = dn;
      bv = fmaxf(bv, dn);
    }
    float bv0 = bv;
#pragma unroll
    for (int off = 1; off < 64; off <<= 1)    // value-only butterfly max
      bv = fmaxf(bv, __shfl_xor(bv, off));
    int bk = 0;
    bool hit = (bv0 == bv);
    if (hit) {                                 // ~15/16 waves execz-skip
#pragma unroll
      for (int k = 7; k >= 0; --k)             // desc scan -> lowest matching k
        if (d[k] == bv0) bk = k;
    }
    unsigned long long m = __ballot(hit);
    int sl = (int)__builtin_ctzll(m);          // lowest lane == lowest index
    int pi = __shfl(t * 8 + bk, sl);
    const int ss = j % 3;
    if (lane == 0) {                           // one keyed atomic per wave
      unsigned long long key =
          ((unsigned long long)f2u(bv) << 32) | (unsigned)(~pi);
      atomicMax(&slots[ss], key);
    }
    if (t == 0) slots[(ss + 1) % 3] = 0ull;    // pre-zero next slot (safe: 3-phase)
    __syncthreads();                           // the ONLY barrier per iteration
    unsigned long long key2 = slots[ss];       // broadcast b64 read
    int gpi = (int)(~(unsigned)key2);
    // winner coords: same-address broadcast (LDS bf path / global f32 path)
    if (BF) {
      int wo3 = gpi * 3;
      p0 = bf2f(sxyz[wo3 + 0]); p1 = bf2f(sxyz[wo3 + 1]); p2 = bf2f(sxyz[wo3 + 2]);
    } else {
      size_t wo = base + (size_t)gpi * 3;
      p0 = ((const float*)xyz)[wo + 0];
      p1 = ((const float*)xyz)[wo + 1];
      p2 = ((const float*)xyz)[wo + 2];
    }
    if (t == (j & 1023)) {                     // bank center j (static slots)
      if ((j >> 10) == 0) { s0x = p0; s0y = p1; s0z = p2; }
      else                { s1x = p0; s1y = p1; s1z = p2; }
    }
  }
  // flush all 2048 selected centers (2 per thread, fully parallel)
  const bool bfrt = BF;
#pragma unroll
  for (int s = 0; s < 2; ++s) {
    float cx = (s==0)?s0x:s1x;
    float cy = (s==0)?s0y:s1y;
    float cz = (s==0)?s0z:s1z;
    size_t o = ((size_t)b * NPOINT_ + s * 1024 + t) * 3;
    nxf[o+0] = cx; nxf[o+1] = cy; nxf[o+2] = cz;
    stf(out, o+0, bfrt, cx); stf(out, o+1, bfrt, cy); stf(out, o+2, bfrt, cz);
  }
}

extern "C" __global__ void __launch_bounds__(1024, 4) fps_kernel(
    const void* xyz, void* out, float* __restrict__ nxf,
    const int* __restrict__ flag) {
  __shared__ unsigned short sxyz[N_ * 3];     // 48KB bf16 mirror (bf path only)
  __shared__ unsigned long long slots[3];     // keyed-max rotation slots
  if (*flag != 0) fps_body<true>(xyz, out, nxf, sxyz, slots);
  else            fps_body<false>(xyz, out, nxf, sxyz, slots);
}

// ---------------- ball query: one wave per center ----------------
extern "C" __global__ void __launch_bounds__(256) ballq_kernel(
    const void* xyz, const float* __restrict__ nxf,
    unsigned short* __restrict__ idxout, const int* __restrict__ flag) {
#pragma clang fp contract(off)
  const bool bf = (*flag != 0);
  const int gw = (int)((blockIdx.x * 256 + threadIdx.x) >> 6);
  const int lane = threadIdx.x & 63;
  const int b = gw >> 11;
  const int j = gw & (NPOINT_ - 1);
  const size_t base = (size_t)b * N_ * 3;
  const size_t co = ((size_t)b * NPOINT_ + j) * 3;
  const float c0 = nxf[co], c1 = nxf[co+1], c2 = nxf[co+2];
  unsigned short* out = idxout + (size_t)gw * NSAMPLE_;
  int cnt = 0, first = 0;
  for (int c = 0; c < N_/64 && cnt < NSAMPLE_; ++c) {
    int i = c * 64 + lane;
    float x = ldf(xyz, base + i*3 + 0, bf);
    float y = ldf(xyz, base + i*3 + 1, bf);
    float z = ldf(xyz, base + i*3 + 2, bf);
    float dx = x - c0, dy = y - c1, dz = z - c2;
    float d2 = (dx*dx + dy*dy) + dz*dz;
    unsigned long long m = __ballot(d2 < 0.16f);
    if (lane == 0) {
      while (m && cnt < NSAMPLE_) {
        int bit = __builtin_ctzll(m);
        int pi = c * 64 + bit;
        if (cnt == 0) first = pi;
        out[cnt] = (unsigned short)pi;
        ++cnt;
        m &= (m - 1);
      }
    }
    cnt = __shfl(cnt, 0);
  }
  first = __shfl(first, 0);
  if (lane >= cnt && lane < NSAMPLE_) out[lane] = (unsigned short)first;
}

// ---------------- shared row-compute building blocks ----------------
// Streams the 64-ch points row in 8-elem chunks (keeps x-liveness at 8 regs).
__device__ __forceinline__ void l1_row(
    const void* xyz, const void* points, const float* __restrict__ nxf,
    const unsigned short* __restrict__ idx, const float* __restrict__ wf,
    int r, bool bf, float* acc) {
  const int b = r >> 16;                       // 65536 rows per batch
  const int j = (r >> 5) & (NPOINT_ - 1);
  const int i = idx[r];
  const size_t pt = (size_t)b * N_ + i;
  const float* cp = nxf + ((size_t)b * NPOINT_ + j) * 3;
  float f0 = ldf(xyz, pt*3 + 0, bf) - cp[0];
  float f1 = ldf(xyz, pt*3 + 1, bf) - cp[1];
  float f2 = ldf(xyz, pt*3 + 2, bf) - cp[2];
#pragma unroll
  for (int c = 0; c < 64; ++c)
    acc[c] = fmaf(f0, wf[c], fmaf(f1, wf[64+c], f2 * wf[128+c]));
  const float* wp = wf + 192;
  if (bf) {
    const uint4* pp = (const uint4*)((const unsigned short*)points + pt * 64);
#pragma unroll
    for (int s = 0; s < 8; ++s) {
      uint4 u = pp[s];
      float x[8]; unpack8(u, x);
#pragma unroll
      for (int kk = 0; kk < 8; ++kk)
#pragma unroll
        for (int c = 0; c < 64; ++c)
          acc[c] = fmaf(x[kk], wp[(s*8+kk)*64 + c], acc[c]);
    }
  } else {
    const float4* pp = (const float4*)((const float*)points + pt * 64);
#pragma unroll
    for (int s = 0; s < 16; ++s) {
      float4 u = pp[s];
      float x[4] = {u.x, u.y, u.z, u.w};
#pragma unroll
      for (int kk = 0; kk < 4; ++kk)
#pragma unroll
        for (int c = 0; c < 64; ++c)
          acc[c] = fmaf(x[kk], wp[(s*4+kk)*64 + c], acc[c]);
    }
  }
}

template <int LDW>
__device__ __forceinline__ void mm64(const float* v, const float* __restrict__ w,
                                     float* acc) {
#pragma unroll
  for (int ch = 0; ch < 64; ++ch)
#pragma unroll
    for (int c = 0; c < 64; ++c)
      acc[c] = fmaf(v[ch], w[ch*LDW + c], acc[c]);
}

__device__ __forceinline__ void bnrelu64(float* v, const float* __restrict__ np0) {
#pragma unroll
  for (int c = 0; c < 64; ++c)
    v[c] = fmaxf(fmaf(v[c], np0[c], np0[64 + c]), 0.f);
}

// wave butterfly-sum of 64-elem array + its squares, LDS combine, block atomics
__device__ __forceinline__ void commit_stats64(float* a, float* __restrict__ stats) {
  float q[64];
#pragma unroll
  for (int c = 0; c < 64; ++c) q[c] = a[c] * a[c];
#pragma unroll
  for (int off = 1; off < 64; off <<= 1)
#pragma unroll
    for (int c = 0; c < 64; ++c) {
      a[c] += __shfl_xor(a[c], off);
      q[c] += __shfl_xor(q[c], off);
    }
  __shared__ float LS[4][64], LQ[4][64];
  const int t = threadIdx.x, w = t >> 6;
  if ((t & 63) == 0) {
#pragma unroll
    for (int c = 0; c < 64; ++c) { LS[w][c] = a[c]; LQ[w][c] = q[c]; }
  }
  __syncthreads();
  if (t < 64) {
    atomicAdd(&stats[t],      LS[0][t] + LS[1][t] + LS[2][t] + LS[3][t]);
    atomicAdd(&stats[64 + t], LQ[0][t] + LQ[1][t] + LQ[2][t] + LQ[3][t]);
  }
}

// ---------------- pass 1: L1 row -> stats only ----------------
extern "C" __global__ void __launch_bounds__(256) p1_kernel(
    const void* xyz, const void* points, const float* __restrict__ nxf,
    const unsigned short* __restrict__ idx, const float* __restrict__ wf,
    float* __restrict__ stats, const int* __restrict__ flag) {
  const bool bf = (*flag != 0);
  const int r = blockIdx.x * 256 + threadIdx.x;
  float acc[64];
  l1_row(xyz, points, nxf, idx, wf, r, bf, acc);
  commit_stats64(acc, stats);
}

// ---------------- pass 2: L1 -> BN1 -> L2 -> stats ----------------
// (256,2): cap 256 VGPRs — v[64]+acc[64]+temps ≈ 140 live floats must not spill
extern "C" __global__ void __launch_bounds__(256, 2) p2_kernel(
    const void* xyz, const void* points, const float* __restrict__ nxf,
    const unsigned short* __restrict__ idx, const float* __restrict__ wf,
    const float* __restrict__ w2, const float* __restrict__ np1,
    float* __restrict__ stats, const int* __restrict__ flag) {
  const bool bf = (*flag != 0);
  const int r = blockIdx.x * 256 + threadIdx.x;
  float v[64];
  l1_row(xyz, points, nxf, idx, wf, r, bf, v);
  bnrelu64(v, np1);
  float acc[64];
#pragma unroll
  for (int c = 0; c < 64; ++c) acc[c] = 0.f;
  mm64<64>(v, w2, acc);
  commit_stats64(acc, stats);
}

// ---------------- pass 3: L1->BN1->L2->BN2->L3 + group max + stats ----------
// (256,2): cap 256 VGPRs — v+y2+y3 = 192 live floats must not spill
extern "C" __global__ void __launch_bounds__(256, 2) p3_kernel(
    const void* xyz, const void* points, const float* __restrict__ nxf,
    const unsigned short* __restrict__ idx, const float* __restrict__ wf,
    const float* __restrict__ w2, const float* __restrict__ w3,
    const float* __restrict__ np1, const float* __restrict__ np2,
    unsigned short* __restrict__ maxb, float* __restrict__ stats,
    const int* __restrict__ flag) {
  const bool bf = (*flag != 0);
  const int t = threadIdx.x, lane = t & 63, w = t >> 6;
  const int h = __builtin_amdgcn_readfirstlane(w & 1);
  const int g = blockIdx.x * 4 + (w >> 1) * 2 + (lane >> 5);
  const int r = g * 32 + (lane & 31);
  float v[64];
  l1_row(xyz, points, nxf, idx, wf, r, bf, v);
  bnrelu64(v, np1);
  float y2[64];
#pragma unroll
  for (int c = 0; c < 64; ++c) y2[c] = 0.f;
  mm64<64>(v, w2, y2);
  bnrelu64(y2, np2);
  const float* w3h = w3 + h * 64;
  float y3[64];
#pragma unroll
  for (int c = 0; c < 64; ++c) y3[c] = 0.f;
  mm64<128>(y2, w3h, y3);
  float* s = v; float* q = y2;                 // reuse registers
#pragma unroll
  for (int c = 0; c < 64; ++c) { s[c] = y3[c]; q[c] = y3[c] * y3[c]; }
  // group max over 32-lane halves on raw y3
#pragma unroll
  for (int off = 1; off <= 16; off <<= 1)
#pragma unroll
    for (int c = 0; c < 64; ++c)
      y3[c] = fmaxf(y3[c], __shfl_xor(y3[c], off));
  if ((lane & 31) == 0) {
    unsigned short* mo = maxb + (size_t)g * 128 + h * 64;
#pragma unroll
    for (int c = 0; c < 64; ++c) mo[c] = f2bf(y3[c]);
  }
  // stats: sum over full wave (both 32-row groups share channel-half h)
#pragma unroll
  for (int off = 1; off < 64; off <<= 1)
#pragma unroll
    for (int c = 0; c < 64; ++c) {
      s[c] += __shfl_xor(s[c], off);
      q[c] += __shfl_xor(q[c], off);
    }
  __shared__ float LS[4][64], LQ[4][64];
  if (lane == 0) {
#pragma unroll
    for (int c = 0; c < 64; ++c) { LS[w][c] = s[c]; LQ[w][c] = q[c]; }
  }
  __syncthreads();
  if (t < 128) {
    int hh = t >> 6, cl = t & 63;
    atomicAdd(&stats[t],       LS[hh][cl] + LS[hh+2][cl]);
    atomicAdd(&stats[128 + t], LQ[hh][cl] + LQ[hh+2][cl]);
  }
}

// ---------------- fold stats into (scale, shift) ----------------
extern "C" __global__ void nparam_kernel(
    const float* __restrict__ stats, const float* __restrict__ g,
    const float* __restrict__ bb, float* __restrict__ npar, int Cc) {
  int c = threadIdx.x;
  if (c < Cc) {
    float m = stats[c] * (1.0f / M_ROWS);
    float v = stats[Cc + c] * (1.0f / M_ROWS) - m * m;
    float sc = g[c] / sqrtf(v + 1e-5f);
    npar[c] = sc;
    npar[Cc + c] = bb[c] - m * sc;
  }
}

// ---------------- final: affine+relu on raw maxima -> out ----------------
extern "C" __global__ void __launch_bounds__(256) final_kernel(
    const unsigned short* __restrict__ maxb, const float* __restrict__ npar,
    void* out, const int* __restrict__ flag) {
  const bool bf = (*flag != 0);
  const int gtid = blockIdx.x * 256 + threadIdx.x;
  const int c = gtid & 127;
  float y = bf2f(maxb[gtid]);
  float r = fmaxf(fmaf(y, npar[c], npar[128 + c]), 0.f);
  stf(out, (size_t)B_ * NPOINT_ * 3 + gtid, bf, r);
}

extern "C" void kernel_launch(void* const* d_in, const int* in_sizes, int n_in,
                              void* d_out, int out_size, void* d_ws, size_t ws_size,
                              hipStream_t stream) {
  const void* xyz    = d_in[0];
  const void* points = d_in[1];
  char* ws = (char*)d_ws;
  float* nxf   = (float*)(ws + OFF_NXF);
  unsigned short* wsIdx = (unsigned short*)(ws + OFF_IDX);
  float* wf    = (float*)(ws + OFF_WF);
  float* gb    = (float*)(ws + OFF_GB);
  float* stats = (float*)(ws + OFF_STATS);
  float* npar  = (float*)(ws + OFF_NP);
  int*   flag  = (int*)(ws + OFF_FLAG);
  unsigned short* maxb = (unsigned short*)(ws + OFF_MAXB);

  hipMemsetAsync(stats, 0, 512 * sizeof(float), stream);
  detect_kernel<<<1, 64, 0, stream>>>((const unsigned short*)xyz, flag);
  prep_kernel<<<67, 256, 0, stream>>>(d_in[2], d_in[5], d_in[8], d_in[3], d_in[4],
                                      d_in[6], d_in[7], d_in[9], d_in[10], wf, gb, flag);
  fps_kernel<<<B_, 1024, 0, stream>>>(xyz, d_out, nxf, flag);
  ballq_kernel<<<(B_ * NPOINT_) / 4, 256, 0, stream>>>(xyz, nxf, wsIdx, flag);
  p1_kernel<<<M_ROWS / 256, 256, 0, stream>>>(xyz, points, nxf, wsIdx, wf, stats, flag);
  nparam_kernel<<<1, 128, 0, stream>>>(stats, gb, gb + 64, npar, 64);
  p2_kernel<<<M_ROWS / 256, 256, 0, stream>>>(xyz, points, nxf, wsIdx, wf, wf + 4288,
                                              npar, stats + 128, flag);
  nparam_kernel<<<1, 128, 0, stream>>>(stats + 128, gb + 128, gb + 192, npar + 128, 64);
  p3_kernel<<<(2 * M_ROWS) / 256, 256, 0, stream>>>(xyz, points, nxf, wsIdx, wf,
                                                    wf + 4288, wf + 8384, npar,
                                                    npar + 128, maxb, stats + 256, flag);
  nparam_kernel<<<1, 128, 0, stream>>>(stats + 256, gb + 256, gb + 384, npar + 256, 128);
  final_kernel<<<(NGROUP * 128) / 256, 256, 0, stream>>>(maxb, npar + 256, d_out, flag);
}